// Round 2
// baseline (125.584 us; speedup 1.0000x reference)
//
#include <hip/hip_runtime.h>
#include <stdint.h>

typedef __bf16 bf16x8 __attribute__((ext_vector_type(8)));
typedef float f32x4 __attribute__((ext_vector_type(4)));

#define EPS 1e-5f

// ---- workspace layout (bytes) ----
#define OFF_STATS 0                        // 16 f32
#define OFF_XHI   256                      // 131072 ushort = 256 KB
#define OFF_XLO   (OFF_XHI + 262144)
#define OFF_Q     (OFF_XLO + 262144)       // q,k,v f32 128x2048 each = 1 MB each
#define OFF_AHI   (OFF_Q + 3145728)        // attn hi 128x2048 ushort = 512 KB
#define OFF_ALO   (OFF_AHI + 524288)
#define OFF_PART  (OFF_ALO + 524288)       // 4 x 128x1024 f32 = 2 MB
#define OFF_PROJ  (OFF_PART + 2097152)     // 512 KB

static __device__ __forceinline__ unsigned short f2b(float f) {
  return __builtin_bit_cast(unsigned short, (__bf16)f);
}
static __device__ __forceinline__ void split2(float f, unsigned short& hi, unsigned short& lo) {
  __bf16 h = (__bf16)f;
  hi = __builtin_bit_cast(unsigned short, h);
  lo = f2b(f - (float)h);
}

__device__ __forceinline__ float wave_red(float v) {
#pragma unroll
  for (int o = 32; o > 0; o >>= 1) v += __shfl_down(v, o);
  return v;
}

// K0: split x into hi/lo bf16, zero stats
__global__ __launch_bounds__(256) void prep_kernel(const float* __restrict__ x,
                                                   ushort* __restrict__ xhi,
                                                   ushort* __restrict__ xlo,
                                                   float* __restrict__ stats) {
  int i = blockIdx.x * 1024 + threadIdx.x * 4;
  float4 v = *(const float4*)(x + i);
  ushort4 h, l;
  split2(v.x, h.x, l.x); split2(v.y, h.y, l.y);
  split2(v.z, h.z, l.z); split2(v.w, h.w, l.w);
  *(ushort4*)(xhi + i) = h;
  *(ushort4*)(xlo + i) = l;
  if (blockIdx.x == 0 && threadIdx.x < 16) stats[threadIdx.x] = 0.f;
}

// K1: fused Q/K/V GEMM, split-precision (hi*hi + hi*lo + lo*hi).
// grid = 3 mats x 32 n-tiles (BN=64). BM=128, K=1024, BK=64.
__global__ __launch_bounds__(256) void qkv_gemm(const ushort* __restrict__ xhi,
                                                const ushort* __restrict__ xlo,
                                                const float* __restrict__ Wq,
                                                const float* __restrict__ Wk,
                                                const float* __restrict__ Wv,
                                                float* __restrict__ qkv,
                                                float* __restrict__ stats) {
  __shared__ alignas(16) ushort Ah[128 * 64];
  __shared__ alignas(16) ushort Al[128 * 64];
  __shared__ alignas(16) ushort Bh[64 * 64];
  __shared__ alignas(16) ushort Bl[64 * 64];
  __shared__ float red[16];

  int mat = blockIdx.x >> 5;
  int nt  = blockIdx.x & 31;
  const float* W = (mat == 0) ? Wq : ((mat == 1) ? Wk : Wv);
  float* outp = qkv + mat * 262144;

  int tid = threadIdx.x;
  int w = tid >> 6, lane = tid & 63;
  int arow[4], acol[4];
#pragma unroll
  for (int i = 0; i < 4; ++i) { int c = i * 256 + tid; arow[i] = c >> 3; acol[i] = c & 7; }
  int wr = tid >> 2, wq = tid & 3;

  f32x4 acc[2][4];
#pragma unroll
  for (int m = 0; m < 2; ++m)
#pragma unroll
    for (int n = 0; n < 4; ++n) acc[m][n] = (f32x4){0.f, 0.f, 0.f, 0.f};

  for (int t = 0; t < 16; ++t) {
    uint4 ah[4], al[4];
#pragma unroll
    for (int i = 0; i < 4; ++i) {
      int off = arow[i] * 1024 + t * 64 + acol[i] * 8;
      ah[i] = *(const uint4*)(xhi + off);
      al[i] = *(const uint4*)(xlo + off);
    }
    float wf[16];
    const float* wbase = W + (nt * 64 + wr) * 1024 + t * 64 + wq * 16;
#pragma unroll
    for (int i = 0; i < 4; ++i) {
      float4 t4 = *(const float4*)(wbase + i * 4);
      wf[4 * i + 0] = t4.x; wf[4 * i + 1] = t4.y; wf[4 * i + 2] = t4.z; wf[4 * i + 3] = t4.w;
    }

    __syncthreads();

#pragma unroll
    for (int i = 0; i < 4; ++i) {
      int sw = arow[i] * 64 + ((acol[i] ^ (arow[i] & 7)) << 3);
      *(uint4*)(&Ah[sw]) = ah[i];
      *(uint4*)(&Al[sw]) = al[i];
    }
    unsigned int wuh[8], wul[8];
#pragma unroll
    for (int j = 0; j < 8; ++j) {
      unsigned short h0, l0, h1, l1;
      split2(wf[2 * j], h0, l0); split2(wf[2 * j + 1], h1, l1);
      wuh[j] = (unsigned int)h0 | ((unsigned int)h1 << 16);
      wul[j] = (unsigned int)l0 | ((unsigned int)l1 << 16);
    }
    {
      int ch0 = wq * 2, ch1 = wq * 2 + 1;
      int s0 = wr * 64 + ((ch0 ^ (wr & 7)) << 3);
      int s1 = wr * 64 + ((ch1 ^ (wr & 7)) << 3);
      *(uint4*)(&Bh[s0]) = (uint4){wuh[0], wuh[1], wuh[2], wuh[3]};
      *(uint4*)(&Bh[s1]) = (uint4){wuh[4], wuh[5], wuh[6], wuh[7]};
      *(uint4*)(&Bl[s0]) = (uint4){wul[0], wul[1], wul[2], wul[3]};
      *(uint4*)(&Bl[s1]) = (uint4){wul[4], wul[5], wul[6], wul[7]};
    }
    __syncthreads();

#pragma unroll
    for (int ks = 0; ks < 2; ++ks) {
      int kc = ks * 4 + (lane >> 4);
      bf16x8 afh[2], afl[2], bfh[4], bfl[4];
#pragma unroll
      for (int m = 0; m < 2; ++m) {
        int r = w * 32 + m * 16 + (lane & 15);
        int sw = r * 64 + ((kc ^ (r & 7)) << 3);
        afh[m] = *(const bf16x8*)(&Ah[sw]);
        afl[m] = *(const bf16x8*)(&Al[sw]);
      }
#pragma unroll
      for (int n = 0; n < 4; ++n) {
        int r = n * 16 + (lane & 15);
        int sw = r * 64 + ((kc ^ (r & 7)) << 3);
        bfh[n] = *(const bf16x8*)(&Bh[sw]);
        bfl[n] = *(const bf16x8*)(&Bl[sw]);
      }
#pragma unroll
      for (int m = 0; m < 2; ++m)
#pragma unroll
        for (int n = 0; n < 4; ++n) {
          acc[m][n] = __builtin_amdgcn_mfma_f32_16x16x32_bf16(afh[m], bfh[n], acc[m][n], 0, 0, 0);
          acc[m][n] = __builtin_amdgcn_mfma_f32_16x16x32_bf16(afh[m], bfl[n], acc[m][n], 0, 0, 0);
          acc[m][n] = __builtin_amdgcn_mfma_f32_16x16x32_bf16(afl[m], bfh[n], acc[m][n], 0, 0, 0);
        }
    }
  }

  float s0 = 0, q0 = 0, s1 = 0, q1 = 0;
#pragma unroll
  for (int m = 0; m < 2; ++m)
#pragma unroll
    for (int n = 0; n < 4; ++n)
#pragma unroll
      for (int r = 0; r < 4; ++r) {
        int row = w * 32 + m * 16 + (lane >> 4) * 4 + r;
        int col = nt * 64 + n * 16 + (lane & 15);
        float v = acc[m][n][r];
        outp[row * 2048 + col] = v;
        if (r & 1) { s1 += v; q1 += v * v; } else { s0 += v; q0 += v * v; }
      }
  s0 = wave_red(s0); q0 = wave_red(q0); s1 = wave_red(s1); q1 = wave_red(q1);
  if (lane == 0) { red[w * 4 + 0] = s0; red[w * 4 + 1] = q0; red[w * 4 + 2] = s1; red[w * 4 + 3] = q1; }
  __syncthreads();
  if (tid == 0) {
    float a0 = 0, a1 = 0, a2 = 0, a3 = 0;
    for (int i = 0; i < 4; ++i) { a0 += red[i * 4 + 0]; a1 += red[i * 4 + 1]; a2 += red[i * 4 + 2]; a3 += red[i * 4 + 3]; }
    atomicAdd(&stats[mat * 4 + 0], a0);
    atomicAdd(&stats[mat * 4 + 1], a1);
    atomicAdd(&stats[mat * 4 + 2], a2);
    atomicAdd(&stats[mat * 4 + 3], a3);
  }
}

// K2: per-(b,h) linear attention with on-the-fly BN affine; writes attn hi/lo bf16.
__global__ __launch_bounds__(256) void attn_kernel(const float* __restrict__ qkv,
                                                   const float* __restrict__ stats,
                                                   ushort* __restrict__ ahi,
                                                   ushort* __restrict__ alo,
                                                   const float* __restrict__ g_q, const float* __restrict__ b_q,
                                                   const float* __restrict__ g_k, const float* __restrict__ b_k,
                                                   const float* __restrict__ g_v, const float* __restrict__ b_v) {
  __shared__ float red[16];
  __shared__ float bc[4];
  int bh = blockIdx.x, b = bh >> 1, h = bh & 1;
  int tid = threadIdx.x, w = tid >> 6, lane = tid & 63;

  const float cnt = 131072.f;
  float qs[2], qo[2], kc_[2], ko[2], vs[2], vo[2];
#pragma unroll
  for (int c = 0; c < 2; ++c) {
    float m, var, inv;
    m = stats[0 + 2 * c] / cnt; var = stats[1 + 2 * c] / cnt - m * m; inv = rsqrtf(var + EPS);
    qs[c] = g_q[c] * inv; qo[c] = b_q[c] - m * qs[c];
    m = stats[4 + 2 * c] / cnt; var = stats[5 + 2 * c] / cnt - m * m; inv = rsqrtf(var + EPS);
    kc_[c] = g_k[c] * inv; ko[c] = b_k[c] - m * kc_[c];
    m = stats[8 + 2 * c] / cnt; var = stats[9 + 2 * c] / cnt - m * m; inv = rsqrtf(var + EPS);
    vs[c] = g_v[c] * inv; vo[c] = b_v[c] - m * vs[c];
  }

  const float* Q = qkv;
  const float* K = qkv + 262144;
  const float* V = qkv + 524288;
  const float* q0p = Q + (b * 2 + 0) * 2048 + h * 1024;
  const float* q1p = Q + (b * 2 + 1) * 2048 + h * 1024;
  const float* k0p = K + (b * 2 + 0) * 2048 + h * 1024;
  const float* k1p = K + (b * 2 + 1) * 2048 + h * 1024;
  const float* v0p = V + (b * 2 + 0) * 2048 + h * 1024;
  const float* v1p = V + (b * 2 + 1) * 2048 + h * 1024;

  float p00 = 0, p01 = 0, p10 = 0, p11 = 0;
#pragma unroll
  for (int i = 0; i < 4; ++i) {
    int d = tid + i * 256;
    float a0 = q0p[d] * qs[0] + qo[0];
    float a1 = q1p[d] * qs[1] + qo[1];
    float c0 = k0p[d] * kc_[0] + ko[0];
    float c1 = k1p[d] * kc_[1] + ko[1];
    p00 += a0 * c0; p01 += a0 * c1; p10 += a1 * c0; p11 += a1 * c1;
  }
  p00 = wave_red(p00); p01 = wave_red(p01); p10 = wave_red(p10); p11 = wave_red(p11);
  if (lane == 0) { red[w * 4 + 0] = p00; red[w * 4 + 1] = p01; red[w * 4 + 2] = p10; red[w * 4 + 3] = p11; }
  __syncthreads();
  if (tid < 4) bc[tid] = red[0 + tid] + red[4 + tid] + red[8 + tid] + red[12 + tid];
  __syncthreads();
  float s00 = bc[0], s01 = bc[1], s10 = bc[2], s11 = bc[3];
  float di0 = 1.f / (s00 + s01), di1 = 1.f / (s10 + s11);
  int o0 = (b * 2 + 0) * 2048 + h * 1024;
  int o1 = (b * 2 + 1) * 2048 + h * 1024;
#pragma unroll
  for (int i = 0; i < 4; ++i) {
    int d = tid + i * 256;
    float v0 = v0p[d] * vs[0] + vo[0];
    float v1 = v1p[d] * vs[1] + vo[1];
    float r0 = (s00 * v0 + s01 * v1) * di0;
    float r1 = (s10 * v0 + s11 * v1) * di1;
    unsigned short h_, l_;
    split2(r0, h_, l_); ahi[o0 + d] = h_; alo[o0 + d] = l_;
    split2(r1, h_, l_); ahi[o1 + d] = h_; alo[o1 + d] = l_;
  }
}

// K3: out GEMM (128x2048 @ Wo^T -> 128x1024), split-precision, K-split 4.
__global__ __launch_bounds__(256) void out_gemm(const ushort* __restrict__ ahi_g,
                                                const ushort* __restrict__ alo_g,
                                                const float* __restrict__ Wo,
                                                float* __restrict__ part) {
  __shared__ alignas(16) ushort Ah[128 * 64];
  __shared__ alignas(16) ushort Al[128 * 64];
  __shared__ alignas(16) ushort Bh[64 * 64];
  __shared__ alignas(16) ushort Bl[64 * 64];
  int nt = blockIdx.x & 15;
  int ksp = blockIdx.x >> 4;
  float* outp = part + ksp * 131072;

  int tid = threadIdx.x, w = tid >> 6, lane = tid & 63;
  int arow[4], acol[4];
#pragma unroll
  for (int i = 0; i < 4; ++i) { int c = i * 256 + tid; arow[i] = c >> 3; acol[i] = c & 7; }
  int wr = tid >> 2, wq = tid & 3;

  f32x4 acc[2][4];
#pragma unroll
  for (int m = 0; m < 2; ++m)
#pragma unroll
    for (int n = 0; n < 4; ++n) acc[m][n] = (f32x4){0.f, 0.f, 0.f, 0.f};

  for (int t = 0; t < 8; ++t) {
    int koff = ksp * 512 + t * 64;
    uint4 ah[4], al[4];
#pragma unroll
    for (int i = 0; i < 4; ++i) {
      int off = arow[i] * 2048 + koff + acol[i] * 8;
      ah[i] = *(const uint4*)(ahi_g + off);
      al[i] = *(const uint4*)(alo_g + off);
    }
    float wf[16];
    const float* wbase = Wo + (nt * 64 + wr) * 2048 + koff + wq * 16;
#pragma unroll
    for (int i = 0; i < 4; ++i) {
      float4 t4 = *(const float4*)(wbase + i * 4);
      wf[4 * i + 0] = t4.x; wf[4 * i + 1] = t4.y; wf[4 * i + 2] = t4.z; wf[4 * i + 3] = t4.w;
    }

    __syncthreads();

#pragma unroll
    for (int i = 0; i < 4; ++i) {
      int sw = arow[i] * 64 + ((acol[i] ^ (arow[i] & 7)) << 3);
      *(uint4*)(&Ah[sw]) = ah[i];
      *(uint4*)(&Al[sw]) = al[i];
    }
    unsigned int wuh[8], wul[8];
#pragma unroll
    for (int j = 0; j < 8; ++j) {
      unsigned short h0, l0, h1, l1;
      split2(wf[2 * j], h0, l0); split2(wf[2 * j + 1], h1, l1);
      wuh[j] = (unsigned int)h0 | ((unsigned int)h1 << 16);
      wul[j] = (unsigned int)l0 | ((unsigned int)l1 << 16);
    }
    {
      int ch0 = wq * 2, ch1 = wq * 2 + 1;
      int s0 = wr * 64 + ((ch0 ^ (wr & 7)) << 3);
      int s1 = wr * 64 + ((ch1 ^ (wr & 7)) << 3);
      *(uint4*)(&Bh[s0]) = (uint4){wuh[0], wuh[1], wuh[2], wuh[3]};
      *(uint4*)(&Bh[s1]) = (uint4){wuh[4], wuh[5], wuh[6], wuh[7]};
      *(uint4*)(&Bl[s0]) = (uint4){wul[0], wul[1], wul[2], wul[3]};
      *(uint4*)(&Bl[s1]) = (uint4){wul[4], wul[5], wul[6], wul[7]};
    }
    __syncthreads();

#pragma unroll
    for (int ks = 0; ks < 2; ++ks) {
      int kc = ks * 4 + (lane >> 4);
      bf16x8 afh[2], afl[2], bfh[4], bfl[4];
#pragma unroll
      for (int m = 0; m < 2; ++m) {
        int r = w * 32 + m * 16 + (lane & 15);
        int sw = r * 64 + ((kc ^ (r & 7)) << 3);
        afh[m] = *(const bf16x8*)(&Ah[sw]);
        afl[m] = *(const bf16x8*)(&Al[sw]);
      }
#pragma unroll
      for (int n = 0; n < 4; ++n) {
        int r = n * 16 + (lane & 15);
        int sw = r * 64 + ((kc ^ (r & 7)) << 3);
        bfh[n] = *(const bf16x8*)(&Bh[sw]);
        bfl[n] = *(const bf16x8*)(&Bl[sw]);
      }
#pragma unroll
      for (int m = 0; m < 2; ++m)
#pragma unroll
        for (int n = 0; n < 4; ++n) {
          acc[m][n] = __builtin_amdgcn_mfma_f32_16x16x32_bf16(afh[m], bfh[n], acc[m][n], 0, 0, 0);
          acc[m][n] = __builtin_amdgcn_mfma_f32_16x16x32_bf16(afh[m], bfl[n], acc[m][n], 0, 0, 0);
          acc[m][n] = __builtin_amdgcn_mfma_f32_16x16x32_bf16(afl[m], bfh[n], acc[m][n], 0, 0, 0);
        }
    }
  }

#pragma unroll
  for (int m = 0; m < 2; ++m)
#pragma unroll
    for (int n = 0; n < 4; ++n)
#pragma unroll
      for (int r = 0; r < 4; ++r) {
        int row = w * 32 + m * 16 + (lane >> 4) * 4 + r;
        int col = nt * 64 + n * 16 + (lane & 15);
        outp[row * 1024 + col] = acc[m][n][r];
      }
}

// K4: reduce K-split partials + bias, write proj, accumulate final-BN stats.
__global__ __launch_bounds__(256) void reduce_kernel(const float* __restrict__ part,
                                                     const float* __restrict__ bo,
                                                     float* __restrict__ proj,
                                                     float* __restrict__ stats) {
  __shared__ float red[8];
  int r = blockIdx.x, tid = threadIdx.x, w = tid >> 6, lane = tid & 63;
  float s = 0, q = 0;
#pragma unroll
  for (int i = 0; i < 4; ++i) {
    int c = tid + i * 256;
    float v = part[r * 1024 + c] + part[131072 + r * 1024 + c] +
              part[262144 + r * 1024 + c] + part[393216 + r * 1024 + c] + bo[c];
    proj[r * 1024 + c] = v;
    s += v; q += v * v;
  }
  s = wave_red(s); q = wave_red(q);
  if (lane == 0) { red[w * 2] = s; red[w * 2 + 1] = q; }
  __syncthreads();
  if (tid == 0) {
    float a = 0, bq = 0;
    for (int i = 0; i < 4; ++i) { a += red[i * 2]; bq += red[i * 2 + 1]; }
    atomicAdd(&stats[12 + 2 * (r & 1)], a);
    atomicAdd(&stats[13 + 2 * (r & 1)], bq);
  }
}

// K5: final BN normalize.
__global__ __launch_bounds__(256) void final_kernel(const float* __restrict__ proj,
                                                    const float* __restrict__ stats,
                                                    const float* __restrict__ g_bn,
                                                    const float* __restrict__ b_bn,
                                                    float* __restrict__ out) {
  int i = blockIdx.x * 1024 + threadIdx.x * 4;
  int ch = (i >> 10) & 1;
  float m = stats[12 + 2 * ch] / 65536.f;
  float var = stats[13 + 2 * ch] / 65536.f - m * m;
  float sc = g_bn[ch] * rsqrtf(var + EPS);
  float sh = b_bn[ch] - m * sc;
  float4 v = *(const float4*)(proj + i);
  float4 o = {v.x * sc + sh, v.y * sc + sh, v.z * sc + sh, v.w * sc + sh};
  *(float4*)(out + i) = o;
}

extern "C" void kernel_launch(void* const* d_in, const int* in_sizes, int n_in,
                              void* d_out, int out_size, void* d_ws, size_t ws_size,
                              hipStream_t stream) {
  (void)in_sizes; (void)n_in; (void)out_size; (void)ws_size;
  const float* x    = (const float*)d_in[0];
  const float* Wq   = (const float*)d_in[1];
  const float* Wk   = (const float*)d_in[2];
  const float* Wv   = (const float*)d_in[3];
  const float* Wo   = (const float*)d_in[4];
  const float* bo   = (const float*)d_in[5];
  const float* g_q  = (const float*)d_in[6];
  const float* b_q  = (const float*)d_in[7];
  const float* g_k  = (const float*)d_in[8];
  const float* b_k  = (const float*)d_in[9];
  const float* g_v  = (const float*)d_in[10];
  const float* b_v  = (const float*)d_in[11];
  const float* g_bn = (const float*)d_in[12];
  const float* b_bn = (const float*)d_in[13];
  char* ws = (char*)d_ws;
  float* out = (float*)d_out;

  float*  stats = (float*)(ws + OFF_STATS);
  ushort* xhi   = (ushort*)(ws + OFF_XHI);
  ushort* xlo   = (ushort*)(ws + OFF_XLO);
  float*  qkv   = (float*)(ws + OFF_Q);
  ushort* ahi   = (ushort*)(ws + OFF_AHI);
  ushort* alo   = (ushort*)(ws + OFF_ALO);
  float*  part  = (float*)(ws + OFF_PART);
  float*  proj  = (float*)(ws + OFF_PROJ);

  hipLaunchKernelGGL(prep_kernel,   dim3(128), dim3(256), 0, stream, x, xhi, xlo, stats);
  hipLaunchKernelGGL(qkv_gemm,      dim3(96),  dim3(256), 0, stream, xhi, xlo, Wq, Wk, Wv, qkv, stats);
  hipLaunchKernelGGL(attn_kernel,   dim3(128), dim3(256), 0, stream, qkv, stats, ahi, alo,
                     g_q, b_q, g_k, b_k, g_v, b_v);
  hipLaunchKernelGGL(out_gemm,      dim3(64),  dim3(256), 0, stream, ahi, alo, Wo, part);
  hipLaunchKernelGGL(reduce_kernel, dim3(128), dim3(256), 0, stream, part, bo, proj, stats);
  hipLaunchKernelGGL(final_kernel,  dim3(128), dim3(256), 0, stream, proj, stats, g_bn, b_bn, out);
}

// Round 3
// 57.816 us; speedup vs baseline: 2.1721x; 2.1721x over previous
//
#include <hip/hip_runtime.h>
#include <stdint.h>

typedef __bf16 bf16x8 __attribute__((ext_vector_type(8)));
typedef float f32x4 __attribute__((ext_vector_type(4)));

#define EPS 1e-5f

// ---- workspace layout (bytes) ----
#define OFF_STATS 0                        // 16 f32
#define OFF_XHI   256                      // 131072 ushort = 256 KB
#define OFF_XLO   (OFF_XHI + 262144)
#define OFF_Q     (OFF_XLO + 262144)       // q,k,v f32 128x2048 each = 1 MB each
#define OFF_AHI   (OFF_Q + 3145728)        // attn hi 128x2048 ushort = 512 KB
#define OFF_ALO   (OFF_AHI + 524288)
#define OFF_PART  (OFF_ALO + 524288)       // 4 x 128x1024 f32 = 2 MB
#define OFF_PROJ  (OFF_PART + 2097152)     // 512 KB

static __device__ __forceinline__ unsigned short f2b(float f) {
  return __builtin_bit_cast(unsigned short, (__bf16)f);
}
static __device__ __forceinline__ void split2(float f, unsigned short& hi, unsigned short& lo) {
  __bf16 h = (__bf16)f;
  hi = __builtin_bit_cast(unsigned short, h);
  lo = f2b(f - (float)h);
}

__device__ __forceinline__ float wave_red(float v) {
#pragma unroll
  for (int o = 32; o > 0; o >>= 1) v += __shfl_down(v, o);
  return v;
}

#define GLDS16(g, l)                                             \
  __builtin_amdgcn_global_load_lds(                              \
      (const __attribute__((address_space(1))) void*)(g),        \
      (__attribute__((address_space(3))) void*)(l), 16, 0, 0)

// K0: split x into hi/lo bf16, zero stats
__global__ __launch_bounds__(256) void prep_kernel(const float* __restrict__ x,
                                                   ushort* __restrict__ xhi,
                                                   ushort* __restrict__ xlo,
                                                   float* __restrict__ stats) {
  int i = blockIdx.x * 1024 + threadIdx.x * 4;
  float4 v = *(const float4*)(x + i);
  ushort4 h, l;
  split2(v.x, h.x, l.x); split2(v.y, h.y, l.y);
  split2(v.z, h.z, l.z); split2(v.w, h.w, l.w);
  *(ushort4*)(xhi + i) = h;
  *(ushort4*)(xlo + i) = l;
  if (blockIdx.x == 0 && threadIdx.x < 16) stats[threadIdx.x] = 0.f;
}

// ---- shared GEMM building blocks (macros for static indexing, rule #20) ----
#define LOADW(WARR, SRC)                         \
  do {                                           \
    float4 a_ = *(const float4*)(SRC);           \
    float4 b_ = *(const float4*)((SRC) + 4);     \
    WARR[0] = a_.x; WARR[1] = a_.y; WARR[2] = a_.z; WARR[3] = a_.w; \
    WARR[4] = b_.x; WARR[5] = b_.y; WARR[6] = b_.z; WARR[7] = b_.w; \
  } while (0)

#define CVT_STORE(BUFIDX, WARR)                                         \
  do {                                                                  \
    uint4 ph_, pl_;                                                     \
    unsigned short h0_, l0_, h1_, l1_;                                  \
    split2(WARR[0], h0_, l0_); split2(WARR[1], h1_, l1_);               \
    ph_.x = (unsigned)h0_ | ((unsigned)h1_ << 16);                      \
    pl_.x = (unsigned)l0_ | ((unsigned)l1_ << 16);                      \
    split2(WARR[2], h0_, l0_); split2(WARR[3], h1_, l1_);               \
    ph_.y = (unsigned)h0_ | ((unsigned)h1_ << 16);                      \
    pl_.y = (unsigned)l0_ | ((unsigned)l1_ << 16);                      \
    split2(WARR[4], h0_, l0_); split2(WARR[5], h1_, l1_);               \
    ph_.z = (unsigned)h0_ | ((unsigned)h1_ << 16);                      \
    pl_.z = (unsigned)l0_ | ((unsigned)l1_ << 16);                      \
    split2(WARR[6], h0_, l0_); split2(WARR[7], h1_, l1_);               \
    ph_.w = (unsigned)h0_ | ((unsigned)h1_ << 16);                      \
    pl_.w = (unsigned)l0_ | ((unsigned)l1_ << 16);                      \
    *(uint4*)(&Bh[BUFIDX][wdst]) = ph_;                                 \
    *(uint4*)(&Bl[BUFIDX][wdst]) = pl_;                                 \
  } while (0)

// K1: fused Q/K/V GEMM, split-precision (hh+hl+lh), depth-2 pipeline.
// BM=128, BN=32, BK=64, K=1024 (16 iters). grid = 3 mats x 64 n-tiles = 192.
__global__ __launch_bounds__(256, 2) void qkv_gemm(const ushort* __restrict__ xhi,
                                                   const ushort* __restrict__ xlo,
                                                   const float* __restrict__ Wq,
                                                   const float* __restrict__ Wk,
                                                   const float* __restrict__ Wv,
                                                   float* __restrict__ qkv,
                                                   float* __restrict__ stats) {
  __shared__ alignas(16) ushort Ah[2][128 * 64];
  __shared__ alignas(16) ushort Al[2][128 * 64];
  __shared__ alignas(16) ushort Bh[2][32 * 64];
  __shared__ alignas(16) ushort Bl[2][32 * 64];
  __shared__ float red[16];

  int mat = blockIdx.x >> 6;
  int nt  = blockIdx.x & 63;
  const float* W = (mat == 0) ? Wq : ((mat == 1) ? Wk : Wv);
  float* outp = qkv + mat * 262144;

  int tid = threadIdx.x, w = tid >> 6, lane = tid & 63;
  int l3 = lane >> 3, c7 = lane & 7;
  int swzc = (c7 ^ (l3 & 7)) << 3;             // pre-swizzled source chunk (elems)
  int wr2 = tid >> 3, wq2 = tid & 7;           // W staging: row, 8-float chunk
  const float* wsrc = W + (nt * 32 + wr2) * 1024 + wq2 * 8;
  int wdst = wr2 * 64 + ((wq2 ^ (wr2 & 7)) << 3);

  f32x4 acc[2][2];
#pragma unroll
  for (int m = 0; m < 2; ++m)
#pragma unroll
    for (int n = 0; n < 2; ++n) acc[m][n] = (f32x4){0.f, 0.f, 0.f, 0.f};

  float wreg0[8], wreg1[8];

  // prologue: stage t=0 -> buf0, t=1 -> buf1
#pragma unroll
  for (int j = 0; j < 4; ++j) {
    int row = (w * 4 + j) * 8 + l3;
    GLDS16(xhi + row * 1024 + 0 * 64 + swzc, &Ah[0][(w * 4 + j) * 512]);
    GLDS16(xlo + row * 1024 + 0 * 64 + swzc, &Al[0][(w * 4 + j) * 512]);
  }
  LOADW(wreg0, wsrc + 0 * 64);
#pragma unroll
  for (int j = 0; j < 4; ++j) {
    int row = (w * 4 + j) * 8 + l3;
    GLDS16(xhi + row * 1024 + 1 * 64 + swzc, &Ah[1][(w * 4 + j) * 512]);
    GLDS16(xlo + row * 1024 + 1 * 64 + swzc, &Al[1][(w * 4 + j) * 512]);
  }
  LOADW(wreg1, wsrc + 1 * 64);
  CVT_STORE(0, wreg0);   // compiler inserts counted vmcnt for wreg0 -> covers buf0 glds too
  __syncthreads();

#pragma unroll
  for (int t = 0; t < 16; ++t) {
    const int c = t & 1;
    // fragment reads from buf c (wave reads ONLY its own 32 A-rows)
    bf16x8 fah[2][2], fal[2][2], fbh[2][2], fbl[2][2];
#pragma unroll
    for (int ks = 0; ks < 2; ++ks) {
      int kc = ks * 4 + (lane >> 4);
#pragma unroll
      for (int m = 0; m < 2; ++m) {
        int r = w * 32 + m * 16 + (lane & 15);
        int sw = r * 64 + ((kc ^ (r & 7)) << 3);
        fah[ks][m] = *(const bf16x8*)(&Ah[c][sw]);
        fal[ks][m] = *(const bf16x8*)(&Al[c][sw]);
      }
#pragma unroll
      for (int n = 0; n < 2; ++n) {
        int r = n * 16 + (lane & 15);
        int sw = r * 64 + ((kc ^ (r & 7)) << 3);
        fbh[ks][n] = *(const bf16x8*)(&Bh[c][sw]);
        fbl[ks][n] = *(const bf16x8*)(&Bl[c][sw]);
      }
    }
    if (t < 14) {
      asm volatile("s_waitcnt lgkmcnt(0)" ::: "memory");  // own reads of buf c done
#pragma unroll
      for (int j = 0; j < 4; ++j) {
        int row = (w * 4 + j) * 8 + l3;
        GLDS16(xhi + row * 1024 + (t + 2) * 64 + swzc, &Ah[c][(w * 4 + j) * 512]);
        GLDS16(xlo + row * 1024 + (t + 2) * 64 + swzc, &Al[c][(w * 4 + j) * 512]);
      }
      if (c == 0) { LOADW(wreg0, wsrc + (t + 2) * 64); }
      else        { LOADW(wreg1, wsrc + (t + 2) * 64); }
    }
#pragma unroll
    for (int ks = 0; ks < 2; ++ks)
#pragma unroll
      for (int m = 0; m < 2; ++m)
#pragma unroll
        for (int n = 0; n < 2; ++n) {
          acc[m][n] = __builtin_amdgcn_mfma_f32_16x16x32_bf16(fah[ks][m], fbh[ks][n], acc[m][n], 0, 0, 0);
          acc[m][n] = __builtin_amdgcn_mfma_f32_16x16x32_bf16(fah[ks][m], fbl[ks][n], acc[m][n], 0, 0, 0);
          acc[m][n] = __builtin_amdgcn_mfma_f32_16x16x32_bf16(fal[ks][m], fbh[ks][n], acc[m][n], 0, 0, 0);
        }
    if (t < 15) {
      if (c == 0) { CVT_STORE(1, wreg1); }   // W(t+1) -> buf (t+1)&1
      else        { CVT_STORE(0, wreg0); }
      __syncthreads();
    }
  }

  // epilogue: store f32 + per-channel stats (channel = row&1 = r&1)
  float s0 = 0, q0 = 0, s1 = 0, q1 = 0;
#pragma unroll
  for (int m = 0; m < 2; ++m)
#pragma unroll
    for (int n = 0; n < 2; ++n)
#pragma unroll
      for (int r = 0; r < 4; ++r) {
        int row = w * 32 + m * 16 + (lane >> 4) * 4 + r;
        int col = nt * 32 + n * 16 + (lane & 15);
        float v = acc[m][n][r];
        outp[row * 2048 + col] = v;
        if (r & 1) { s1 += v; q1 += v * v; } else { s0 += v; q0 += v * v; }
      }
  s0 = wave_red(s0); q0 = wave_red(q0); s1 = wave_red(s1); q1 = wave_red(q1);
  if (lane == 0) { red[w * 4 + 0] = s0; red[w * 4 + 1] = q0; red[w * 4 + 2] = s1; red[w * 4 + 3] = q1; }
  __syncthreads();
  if (tid == 0) {
    float a0 = 0, a1 = 0, a2 = 0, a3 = 0;
    for (int i = 0; i < 4; ++i) { a0 += red[i * 4 + 0]; a1 += red[i * 4 + 1]; a2 += red[i * 4 + 2]; a3 += red[i * 4 + 3]; }
    atomicAdd(&stats[mat * 4 + 0], a0);
    atomicAdd(&stats[mat * 4 + 1], a1);
    atomicAdd(&stats[mat * 4 + 2], a2);
    atomicAdd(&stats[mat * 4 + 3], a3);
  }
}

// K2: per-(b,h) linear attention with on-the-fly BN affine; writes attn hi/lo bf16.
__global__ __launch_bounds__(256) void attn_kernel(const float* __restrict__ qkv,
                                                   const float* __restrict__ stats,
                                                   ushort* __restrict__ ahi,
                                                   ushort* __restrict__ alo,
                                                   const float* __restrict__ g_q, const float* __restrict__ b_q,
                                                   const float* __restrict__ g_k, const float* __restrict__ b_k,
                                                   const float* __restrict__ g_v, const float* __restrict__ b_v) {
  __shared__ float red[16];
  __shared__ float bc[4];
  int bh = blockIdx.x, b = bh >> 1, h = bh & 1;
  int tid = threadIdx.x, w = tid >> 6, lane = tid & 63;

  const float cnt = 131072.f;
  float qs[2], qo[2], kc_[2], ko[2], vs[2], vo[2];
#pragma unroll
  for (int c = 0; c < 2; ++c) {
    float m, var, inv;
    m = stats[0 + 2 * c] / cnt; var = stats[1 + 2 * c] / cnt - m * m; inv = rsqrtf(var + EPS);
    qs[c] = g_q[c] * inv; qo[c] = b_q[c] - m * qs[c];
    m = stats[4 + 2 * c] / cnt; var = stats[5 + 2 * c] / cnt - m * m; inv = rsqrtf(var + EPS);
    kc_[c] = g_k[c] * inv; ko[c] = b_k[c] - m * kc_[c];
    m = stats[8 + 2 * c] / cnt; var = stats[9 + 2 * c] / cnt - m * m; inv = rsqrtf(var + EPS);
    vs[c] = g_v[c] * inv; vo[c] = b_v[c] - m * vs[c];
  }

  const float* Q = qkv;
  const float* K = qkv + 262144;
  const float* V = qkv + 524288;
  const float* q0p = Q + (b * 2 + 0) * 2048 + h * 1024;
  const float* q1p = Q + (b * 2 + 1) * 2048 + h * 1024;
  const float* k0p = K + (b * 2 + 0) * 2048 + h * 1024;
  const float* k1p = K + (b * 2 + 1) * 2048 + h * 1024;
  const float* v0p = V + (b * 2 + 0) * 2048 + h * 1024;
  const float* v1p = V + (b * 2 + 1) * 2048 + h * 1024;

  float p00 = 0, p01 = 0, p10 = 0, p11 = 0;
#pragma unroll
  for (int i = 0; i < 4; ++i) {
    int d = tid + i * 256;
    float a0 = q0p[d] * qs[0] + qo[0];
    float a1 = q1p[d] * qs[1] + qo[1];
    float c0 = k0p[d] * kc_[0] + ko[0];
    float c1 = k1p[d] * kc_[1] + ko[1];
    p00 += a0 * c0; p01 += a0 * c1; p10 += a1 * c0; p11 += a1 * c1;
  }
  p00 = wave_red(p00); p01 = wave_red(p01); p10 = wave_red(p10); p11 = wave_red(p11);
  if (lane == 0) { red[w * 4 + 0] = p00; red[w * 4 + 1] = p01; red[w * 4 + 2] = p10; red[w * 4 + 3] = p11; }
  __syncthreads();
  if (tid < 4) bc[tid] = red[0 + tid] + red[4 + tid] + red[8 + tid] + red[12 + tid];
  __syncthreads();
  float s00 = bc[0], s01 = bc[1], s10 = bc[2], s11 = bc[3];
  float di0 = 1.f / (s00 + s01), di1 = 1.f / (s10 + s11);
  int o0 = (b * 2 + 0) * 2048 + h * 1024;
  int o1 = (b * 2 + 1) * 2048 + h * 1024;
#pragma unroll
  for (int i = 0; i < 4; ++i) {
    int d = tid + i * 256;
    float v0 = v0p[d] * vs[0] + vo[0];
    float v1 = v1p[d] * vs[1] + vo[1];
    float r0 = (s00 * v0 + s01 * v1) * di0;
    float r1 = (s10 * v0 + s11 * v1) * di1;
    unsigned short h_, l_;
    split2(r0, h_, l_); ahi[o0 + d] = h_; alo[o0 + d] = l_;
    split2(r1, h_, l_); ahi[o1 + d] = h_; alo[o1 + d] = l_;
  }
}

// K3: out GEMM (128x2048 @ Wo^T -> 128x1024), split-precision, depth-2 pipeline.
// BM=128, BN=32, BK=64, Ksplit=4 (K=512/block, 8 iters). grid = 32 nt x 4 ks = 128.
__global__ __launch_bounds__(256, 2) void out_gemm(const ushort* __restrict__ ahi_g,
                                                   const ushort* __restrict__ alo_g,
                                                   const float* __restrict__ Wo,
                                                   float* __restrict__ part) {
  __shared__ alignas(16) ushort Ah[2][128 * 64];
  __shared__ alignas(16) ushort Al[2][128 * 64];
  __shared__ alignas(16) ushort Bh[2][32 * 64];
  __shared__ alignas(16) ushort Bl[2][32 * 64];

  int nt  = blockIdx.x & 31;
  int ksp = blockIdx.x >> 5;
  float* outp = part + ksp * 131072;
  int kbase = ksp * 512;

  int tid = threadIdx.x, w = tid >> 6, lane = tid & 63;
  int l3 = lane >> 3, c7 = lane & 7;
  int swzc = (c7 ^ (l3 & 7)) << 3;
  int wr2 = tid >> 3, wq2 = tid & 7;
  const float* wsrc = Wo + (nt * 32 + wr2) * 2048 + kbase + wq2 * 8;
  int wdst = wr2 * 64 + ((wq2 ^ (wr2 & 7)) << 3);

  f32x4 acc[2][2];
#pragma unroll
  for (int m = 0; m < 2; ++m)
#pragma unroll
    for (int n = 0; n < 2; ++n) acc[m][n] = (f32x4){0.f, 0.f, 0.f, 0.f};

  float wreg0[8], wreg1[8];

#pragma unroll
  for (int j = 0; j < 4; ++j) {
    int row = (w * 4 + j) * 8 + l3;
    GLDS16(ahi_g + row * 2048 + kbase + 0 * 64 + swzc, &Ah[0][(w * 4 + j) * 512]);
    GLDS16(alo_g + row * 2048 + kbase + 0 * 64 + swzc, &Al[0][(w * 4 + j) * 512]);
  }
  LOADW(wreg0, wsrc + 0 * 64);
#pragma unroll
  for (int j = 0; j < 4; ++j) {
    int row = (w * 4 + j) * 8 + l3;
    GLDS16(ahi_g + row * 2048 + kbase + 1 * 64 + swzc, &Ah[1][(w * 4 + j) * 512]);
    GLDS16(alo_g + row * 2048 + kbase + 1 * 64 + swzc, &Al[1][(w * 4 + j) * 512]);
  }
  LOADW(wreg1, wsrc + 1 * 64);
  CVT_STORE(0, wreg0);
  __syncthreads();

#pragma unroll
  for (int t = 0; t < 8; ++t) {
    const int c = t & 1;
    bf16x8 fah[2][2], fal[2][2], fbh[2][2], fbl[2][2];
#pragma unroll
    for (int ks = 0; ks < 2; ++ks) {
      int kc = ks * 4 + (lane >> 4);
#pragma unroll
      for (int m = 0; m < 2; ++m) {
        int r = w * 32 + m * 16 + (lane & 15);
        int sw = r * 64 + ((kc ^ (r & 7)) << 3);
        fah[ks][m] = *(const bf16x8*)(&Ah[c][sw]);
        fal[ks][m] = *(const bf16x8*)(&Al[c][sw]);
      }
#pragma unroll
      for (int n = 0; n < 2; ++n) {
        int r = n * 16 + (lane & 15);
        int sw = r * 64 + ((kc ^ (r & 7)) << 3);
        fbh[ks][n] = *(const bf16x8*)(&Bh[c][sw]);
        fbl[ks][n] = *(const bf16x8*)(&Bl[c][sw]);
      }
    }
    if (t < 6) {
      asm volatile("s_waitcnt lgkmcnt(0)" ::: "memory");
#pragma unroll
      for (int j = 0; j < 4; ++j) {
        int row = (w * 4 + j) * 8 + l3;
        GLDS16(ahi_g + row * 2048 + kbase + (t + 2) * 64 + swzc, &Ah[c][(w * 4 + j) * 512]);
        GLDS16(alo_g + row * 2048 + kbase + (t + 2) * 64 + swzc, &Al[c][(w * 4 + j) * 512]);
      }
      if (c == 0) { LOADW(wreg0, wsrc + (t + 2) * 64); }
      else        { LOADW(wreg1, wsrc + (t + 2) * 64); }
    }
#pragma unroll
    for (int ks = 0; ks < 2; ++ks)
#pragma unroll
      for (int m = 0; m < 2; ++m)
#pragma unroll
        for (int n = 0; n < 2; ++n) {
          acc[m][n] = __builtin_amdgcn_mfma_f32_16x16x32_bf16(fah[ks][m], fbh[ks][n], acc[m][n], 0, 0, 0);
          acc[m][n] = __builtin_amdgcn_mfma_f32_16x16x32_bf16(fah[ks][m], fbl[ks][n], acc[m][n], 0, 0, 0);
          acc[m][n] = __builtin_amdgcn_mfma_f32_16x16x32_bf16(fal[ks][m], fbh[ks][n], acc[m][n], 0, 0, 0);
        }
    if (t < 7) {
      if (c == 0) { CVT_STORE(1, wreg1); }
      else        { CVT_STORE(0, wreg0); }
      __syncthreads();
    }
  }

#pragma unroll
  for (int m = 0; m < 2; ++m)
#pragma unroll
    for (int n = 0; n < 2; ++n)
#pragma unroll
      for (int r = 0; r < 4; ++r) {
        int row = w * 32 + m * 16 + (lane >> 4) * 4 + r;
        int col = nt * 32 + n * 16 + (lane & 15);
        outp[row * 1024 + col] = acc[m][n][r];
      }
}

// K4: reduce K-split partials + bias, write proj, accumulate final-BN stats.
__global__ __launch_bounds__(256) void reduce_kernel(const float* __restrict__ part,
                                                     const float* __restrict__ bo,
                                                     float* __restrict__ proj,
                                                     float* __restrict__ stats) {
  __shared__ float red[8];
  int r = blockIdx.x, tid = threadIdx.x, w = tid >> 6, lane = tid & 63;
  float s = 0, q = 0;
#pragma unroll
  for (int i = 0; i < 4; ++i) {
    int c = tid + i * 256;
    float v = part[r * 1024 + c] + part[131072 + r * 1024 + c] +
              part[262144 + r * 1024 + c] + part[393216 + r * 1024 + c] + bo[c];
    proj[r * 1024 + c] = v;
    s += v; q += v * v;
  }
  s = wave_red(s); q = wave_red(q);
  if (lane == 0) { red[w * 2] = s; red[w * 2 + 1] = q; }
  __syncthreads();
  if (tid == 0) {
    float a = 0, bq = 0;
    for (int i = 0; i < 4; ++i) { a += red[i * 2]; bq += red[i * 2 + 1]; }
    atomicAdd(&stats[12 + 2 * (r & 1)], a);
    atomicAdd(&stats[13 + 2 * (r & 1)], bq);
  }
}

// K5: final BN normalize.
__global__ __launch_bounds__(256) void final_kernel(const float* __restrict__ proj,
                                                    const float* __restrict__ stats,
                                                    const float* __restrict__ g_bn,
                                                    const float* __restrict__ b_bn,
                                                    float* __restrict__ out) {
  int i = blockIdx.x * 1024 + threadIdx.x * 4;
  int ch = (i >> 10) & 1;
  float m = stats[12 + 2 * ch] / 65536.f;
  float var = stats[13 + 2 * ch] / 65536.f - m * m;
  float sc = g_bn[ch] * rsqrtf(var + EPS);
  float sh = b_bn[ch] - m * sc;
  float4 v = *(const float4*)(proj + i);
  float4 o = {v.x * sc + sh, v.y * sc + sh, v.z * sc + sh, v.w * sc + sh};
  *(float4*)(out + i) = o;
}

extern "C" void kernel_launch(void* const* d_in, const int* in_sizes, int n_in,
                              void* d_out, int out_size, void* d_ws, size_t ws_size,
                              hipStream_t stream) {
  (void)in_sizes; (void)n_in; (void)out_size; (void)ws_size;
  const float* x    = (const float*)d_in[0];
  const float* Wq   = (const float*)d_in[1];
  const float* Wk   = (const float*)d_in[2];
  const float* Wv   = (const float*)d_in[3];
  const float* Wo   = (const float*)d_in[4];
  const float* bo   = (const float*)d_in[5];
  const float* g_q  = (const float*)d_in[6];
  const float* b_q  = (const float*)d_in[7];
  const float* g_k  = (const float*)d_in[8];
  const float* b_k  = (const float*)d_in[9];
  const float* g_v  = (const float*)d_in[10];
  const float* b_v  = (const float*)d_in[11];
  const float* g_bn = (const float*)d_in[12];
  const float* b_bn = (const float*)d_in[13];
  char* ws = (char*)d_ws;
  float* out = (float*)d_out;

  float*  stats = (float*)(ws + OFF_STATS);
  ushort* xhi   = (ushort*)(ws + OFF_XHI);
  ushort* xlo   = (ushort*)(ws + OFF_XLO);
  float*  qkv   = (float*)(ws + OFF_Q);
  ushort* ahi   = (ushort*)(ws + OFF_AHI);
  ushort* alo   = (ushort*)(ws + OFF_ALO);
  float*  part  = (float*)(ws + OFF_PART);
  float*  proj  = (float*)(ws + OFF_PROJ);

  hipLaunchKernelGGL(prep_kernel,   dim3(128), dim3(256), 0, stream, x, xhi, xlo, stats);
  hipLaunchKernelGGL(qkv_gemm,      dim3(192), dim3(256), 0, stream, xhi, xlo, Wq, Wk, Wv, qkv, stats);
  hipLaunchKernelGGL(attn_kernel,   dim3(128), dim3(256), 0, stream, qkv, stats, ahi, alo,
                     g_q, b_q, g_k, b_k, g_v, b_v);
  hipLaunchKernelGGL(out_gemm,      dim3(128), dim3(256), 0, stream, ahi, alo, Wo, part);
  hipLaunchKernelGGL(reduce_kernel, dim3(128), dim3(256), 0, stream, part, bo, proj, stats);
  hipLaunchKernelGGL(final_kernel,  dim3(128), dim3(256), 0, stream, proj, stats, g_bn, b_bn, out);
}